// Round 1
// baseline (826.719 us; speedup 1.0000x reference)
//
#include <hip/hip_runtime.h>
#include <hip/hip_bf16.h>

#define LL 512
#define DD 1024
#define HH 8
#define DKK 128
#define QQ 256
#define CCC 128
#define TTT 128
#define RR 50
#define FFF 4096

// ---------------- LayerNorm: one block per row ----------------
__global__ __launch_bounds__(256) void ln_kernel(const float* __restrict__ x,
    const float* __restrict__ g, const float* __restrict__ b,
    float* __restrict__ y)
{
  int row = blockIdx.x, t = threadIdx.x;
  const float4 xv = ((const float4*)(x + row*DD))[t];
  float s  = xv.x+xv.y+xv.z+xv.w;
  float ss = xv.x*xv.x+xv.y*xv.y+xv.z*xv.z+xv.w*xv.w;
  __shared__ float rs[256], rss[256];
  rs[t]=s; rss[t]=ss; __syncthreads();
  for (int st=128; st>0; st>>=1){ if (t<st){ rs[t]+=rs[t+st]; rss[t]+=rss[t+st]; } __syncthreads(); }
  float mean = rs[0] * (1.0f/DD);
  float var  = rss[0]*(1.0f/DD) - mean*mean;
  float inv  = rsqrtf(var + 1e-5f);
  float4 gv = ((const float4*)g)[t], bv = ((const float4*)b)[t];
  float4 ov;
  ov.x = (xv.x-mean)*inv*gv.x + bv.x;
  ov.y = (xv.y-mean)*inv*gv.y + bv.y;
  ov.z = (xv.z-mean)*inv*gv.z + bv.z;
  ov.w = (xv.w-mean)*inv*gv.w + bv.w;
  ((float4*)(y + row*DD))[t] = ov;
}

// ---------------- GEMM: C[M,N] = A[M,K] @ B[N,K]^T + bias (+src) (relu?) ----
// 32x64 tile, BK=16, 256 threads, 2x4 micro-tile
__global__ __launch_bounds__(256) void gemm_nt(
    const float* __restrict__ A, const float* __restrict__ B,
    const float* __restrict__ bias, const float* __restrict__ src,
    float* __restrict__ C, int M, int N, int K, int relu)
{
  __shared__ float As[16][33];
  __shared__ float Bs[16][65];
  int t = threadIdx.x;
  int bm = blockIdx.y * 32;
  int bn = blockIdx.x * 64;
  int tx = t & 15, ty = t >> 4;
  int am = t >> 3, ak = (t & 7) * 2;
  int bn2 = t >> 2, bk = (t & 3) * 4;
  float acc[2][4] = {{0,0,0,0},{0,0,0,0}};
  const float* Ap = A + (size_t)(bm+am)*K + ak;
  const float* Bp = B + (size_t)(bn+bn2)*K + bk;
  for (int k0=0; k0<K; k0+=16) {
    float2 av = *(const float2*)(Ap + k0);
    float4 bv = *(const float4*)(Bp + k0);
    As[ak][am]=av.x; As[ak+1][am]=av.y;
    Bs[bk][bn2]=bv.x; Bs[bk+1][bn2]=bv.y; Bs[bk+2][bn2]=bv.z; Bs[bk+3][bn2]=bv.w;
    __syncthreads();
    #pragma unroll
    for (int kk=0; kk<16; ++kk) {
      float a0=As[kk][ty], a1=As[kk][16+ty];
      float b0=Bs[kk][tx], b1=Bs[kk][16+tx], b2=Bs[kk][32+tx], b3=Bs[kk][48+tx];
      acc[0][0]+=a0*b0; acc[0][1]+=a0*b1; acc[0][2]+=a0*b2; acc[0][3]+=a0*b3;
      acc[1][0]+=a1*b0; acc[1][1]+=a1*b1; acc[1][2]+=a1*b2; acc[1][3]+=a1*b3;
    }
    __syncthreads();
  }
  #pragma unroll
  for (int a=0;a<2;++a)
    #pragma unroll
    for (int bb=0;bb<4;++bb) {
      int row = bm + a*16+ty, col = bn + bb*16+tx;
      float vv = acc[a][bb] + bias[col];
      if (src)  vv += src[(size_t)row*N+col];
      if (relu) vv = fmaxf(vv, 0.0f);
      C[(size_t)row*N+col] = vv;
    }
}

// ---------------- transpose k -> kt[h][d][j] ----------------
__global__ __launch_bounds__(256) void transpose_k(const float* __restrict__ k,
                                                   float* __restrict__ kt)
{
  int g = blockIdx.x*256 + threadIdx.x;      // 512*1024 total
  int j = g & 511; int d = (g >> 9) & 127; int h = g >> 16;
  kt[g] = k[j*DD + h*DKK + d];
}

// ---------------- qe[i,h,r] = q[i,h,:] . emb_k[r,:] ----------------
__global__ __launch_bounds__(64) void qe_kernel(const float* __restrict__ q,
    const float* __restrict__ embk, float* __restrict__ qe)
{
  int i = blockIdx.x, h = blockIdx.y, t = threadIdx.x;
  __shared__ float qrow[128];
  qrow[t]    = q[i*DD + h*DKK + t];
  qrow[t+64] = q[i*DD + h*DKK + t + 64];
  __syncthreads();
  if (t < RR) {
    float s = 0.f;
    #pragma unroll 8
    for (int d=0; d<128; ++d) s += qrow[d]*embk[t*128+d];
    qe[(i*HH+h)*RR + t] = s;
  }
}

// ---------------- ql[tb][i][h][f] = q[i,h,:] . ltab[f,:] ----------------
__global__ __launch_bounds__(256) void ql_kernel(const float* __restrict__ q,
    const float* __restrict__ lqc, const float* __restrict__ lqt,
    const float* __restrict__ lcq, const float* __restrict__ ltq,
    float* __restrict__ ql)
{
  int g = blockIdx.x*256 + threadIdx.x;      // 4*512*8*3 = 49152
  if (g >= 4*LL*HH*3) return;
  int f = g % 3; int h = (g/3) & 7; int i = (g/24) & 511; int tb = g / 12288;
  const float* tab = (tb==0) ? lqc : (tb==1) ? lqt : (tb==2) ? lcq : ltq;
  const float* qr = q + i*DD + h*DKK;
  const float* tr = tab + f*128;
  float s = 0.f;
  #pragma unroll 8
  for (int d=0; d<128; ++d) s += qr[d]*tr[d];
  ql[g] = s;
}

// ---------------- scores + softmax: one block per (i,h), 512 threads -------
__global__ __launch_bounds__(512) void scores_kernel(
    const float* __restrict__ q,  const float* __restrict__ kt,
    const float* __restrict__ qe, const float* __restrict__ ql,
    const float* __restrict__ qcr, const float* __restrict__ cqr,
    const float* __restrict__ qtr, const float* __restrict__ tqr,
    const int* __restrict__ ct,   const int* __restrict__ pred,
    const int* __restrict__ mask, float* __restrict__ P)
{
  int i = blockIdx.x, h = blockIdx.y, j = threadIdx.x;
  __shared__ float qrow[128];
  __shared__ float qerow[52];
  __shared__ float red[512];
  if (j < 128) qrow[j] = q[i*DD + h*DKK + j];
  if (j >= 128 && j < 128+RR) qerow[j-128] = qe[(i*HH+h)*RR + (j-128)];
  __syncthreads();

  float lq1[3] = {0,0,0}, lq2[3] = {0,0,0};
  if (i < QQ) {
    #pragma unroll
    for (int f=0; f<3; ++f) {
      lq1[f] = ql[((0*LL + i)*HH + h)*3 + f];   // qc
      lq2[f] = ql[((1*LL + i)*HH + h)*3 + f];   // qt
    }
  } else if (i < QQ+CCC) {
    #pragma unroll
    for (int f=0; f<3; ++f) lq1[f] = ql[((2*LL + i)*HH + h)*3 + f]; // cq
  } else {
    #pragma unroll
    for (int f=0; f<3; ++f) lq1[f] = ql[((3*LL + i)*HH + h)*3 + f]; // tq
  }

  float s = 0.f;
  const float* kcol = kt + (h*DKK)*LL + j;
  #pragma unroll 8
  for (int d=0; d<128; ++d) s += qrow[d]*kcol[d*LL];

  s += qerow[pred[i*LL + j]];
  if (i < QQ) {
    if (j < QQ) s += qerow[0];
    else if (j < QQ+CCC) { const float* r = qcr + (i*CCC + (j-QQ))*3;
      s += r[0]*lq1[0]+r[1]*lq1[1]+r[2]*lq1[2]; }
    else { const float* r = qtr + (i*TTT + (j-QQ-CCC))*3;
      s += r[0]*lq2[0]+r[1]*lq2[1]+r[2]*lq2[2]; }
  } else {
    if (j < QQ) {
      const float* r = (i < QQ+CCC) ? cqr + ((i-QQ)*QQ + j)*3
                                    : tqr + ((i-QQ-CCC)*QQ + j)*3;
      s += r[0]*lq1[0]+r[1]*lq1[1]+r[2]*lq1[2];
    } else {
      s += qerow[ct[(i-QQ)*(CCC+TTT) + (j-QQ)]];
    }
  }
  s *= 0.08838834764831845f;   // 1/sqrt(128)
  if (mask[i*LL + j] == 0) s = -1e9f;

  red[j] = s; __syncthreads();
  for (int st=256; st>0; st>>=1){ if (j<st) red[j]=fmaxf(red[j],red[j+st]); __syncthreads(); }
  float mx = red[0]; __syncthreads();
  float e = __expf(s - mx);
  red[j] = e; __syncthreads();
  for (int st=256; st>0; st>>=1){ if (j<st) red[j]+=red[j+st]; __syncthreads(); }
  float inv = 1.0f/red[0];
  P[((size_t)h*LL + i)*LL + j] = e*inv;
}

// ---------------- attention output: P@v + P@rel_v (factorized) -------------
__global__ __launch_bounds__(128) void attnout_kernel(
    const float* __restrict__ P,    const float* __restrict__ v,
    const float* __restrict__ embv,
    const float* __restrict__ lqc_v, const float* __restrict__ lcq_v,
    const float* __restrict__ lqt_v, const float* __restrict__ ltq_v,
    const float* __restrict__ qcr,  const float* __restrict__ cqr,
    const float* __restrict__ qtr,  const float* __restrict__ tqr,
    const int* __restrict__ ct,    const int* __restrict__ pred,
    float* __restrict__ obuf)
{
  int i = blockIdx.x, h = blockIdx.y, t = threadIdx.x;  // 128 threads
  __shared__ float pr[512];
  __shared__ float pw[52];
  __shared__ float pf1[3], pf2[3];
  const float* Prow = P + ((size_t)h*LL + i)*LL;
  for (int j=t; j<LL; j+=128) pr[j] = Prow[j];
  if (t < 52) pw[t] = 0.f;
  if (t < 3) { pf1[t]=0.f; pf2[t]=0.f; }
  __syncthreads();

  float lpw0 = 0.f, l1[3] = {0,0,0}, l2[3] = {0,0,0};
  for (int j=t; j<LL; j+=128) {
    float p = pr[j];
    atomicAdd(&pw[pred[i*LL + j]], p);
    if (i < QQ) {
      if (j < QQ) lpw0 += p;
      else if (j < QQ+CCC) { const float* r = qcr + (i*CCC + (j-QQ))*3;
        l1[0]+=p*r[0]; l1[1]+=p*r[1]; l1[2]+=p*r[2]; }
      else { const float* r = qtr + (i*TTT + (j-QQ-CCC))*3;
        l2[0]+=p*r[0]; l2[1]+=p*r[1]; l2[2]+=p*r[2]; }
    } else {
      if (j < QQ) {
        const float* r = (i < QQ+CCC) ? cqr + ((i-QQ)*QQ + j)*3
                                      : tqr + ((i-QQ-CCC)*QQ + j)*3;
        l1[0]+=p*r[0]; l1[1]+=p*r[1]; l1[2]+=p*r[2];
      } else {
        atomicAdd(&pw[ct[(i-QQ)*(CCC+TTT) + (j-QQ)]], p);
      }
    }
  }
  if (i < QQ) atomicAdd(&pw[0], lpw0);
  atomicAdd(&pf1[0], l1[0]); atomicAdd(&pf1[1], l1[1]); atomicAdd(&pf1[2], l1[2]);
  atomicAdd(&pf2[0], l2[0]); atomicAdd(&pf2[1], l2[1]); atomicAdd(&pf2[2], l2[2]);
  __syncthreads();

  const float* tab1; const float* tab2 = nullptr;
  if (i < QQ)          { tab1 = lqc_v; tab2 = lqt_v; }
  else if (i < QQ+CCC) { tab1 = lcq_v; }
  else                 { tab1 = ltq_v; }

  float acc = 0.f;
  const float* vcol = v + h*DKK + t;
  #pragma unroll 4
  for (int j=0; j<LL; ++j) acc += pr[j]*vcol[(size_t)j*DD];
  #pragma unroll 2
  for (int r=0; r<RR; ++r) acc += pw[r]*embv[r*128 + t];
  acc += pf1[0]*tab1[t] + pf1[1]*tab1[128+t] + pf1[2]*tab1[256+t];
  if (tab2) acc += pf2[0]*tab2[t] + pf2[1]*tab2[128+t] + pf2[2]*tab2[256+t];
  obuf[i*DD + h*DKK + t] = acc;
}

// ---------------- launch ----------------
extern "C" void kernel_launch(void* const* d_in, const int* in_sizes, int n_in,
                              void* d_out, int out_size, void* d_ws, size_t ws_size,
                              hipStream_t stream)
{
  const float* x    = (const float*)d_in[0];
  const float* qcr  = (const float*)d_in[1];
  const float* cqr  = (const float*)d_in[2];
  const float* qtr  = (const float*)d_in[3];
  const float* tqr  = (const float*)d_in[4];
  const int*   ct   = (const int*)d_in[5];
  const int*   pred = (const int*)d_in[6];
  const int*   mask = (const int*)d_in[7];
  const float* embk = (const float*)d_in[8];
  const float* embv = (const float*)d_in[9];
  const float* lqc_k = (const float*)d_in[10];
  const float* lqc_v = (const float*)d_in[11];
  const float* lcq_k = (const float*)d_in[12];
  const float* lcq_v = (const float*)d_in[13];
  const float* lqt_k = (const float*)d_in[14];
  const float* lqt_v = (const float*)d_in[15];
  const float* ltq_k = (const float*)d_in[16];
  const float* ltq_v = (const float*)d_in[17];
  const float* Wq = (const float*)d_in[18]; const float* bq = (const float*)d_in[19];
  const float* Wk = (const float*)d_in[20]; const float* bk = (const float*)d_in[21];
  const float* Wv = (const float*)d_in[22]; const float* bv = (const float*)d_in[23];
  const float* Wo = (const float*)d_in[24]; const float* bo = (const float*)d_in[25];
  const float* ln1_g = (const float*)d_in[26]; const float* ln1_b = (const float*)d_in[27];
  const float* ln2_g = (const float*)d_in[28]; const float* ln2_b = (const float*)d_in[29];
  const float* W1 = (const float*)d_in[30]; const float* b1 = (const float*)d_in[31];
  const float* W2 = (const float*)d_in[32]; const float* b2 = (const float*)d_in[33];
  float* out = (float*)d_out;

  float* ws   = (float*)d_ws;
  float* ybuf = ws;                    // [L,D] ln1 out; later reused as obuf
  float* qb   = ybuf + LL*DD;          // [L,D] q; later reused as y2
  float* kb   = qb   + LL*DD;          // [L,D] k
  float* vb   = kb   + LL*DD;          // [L,D] v
  float* ktb  = vb   + LL*DD;          // [H,DK,L]
  float* qe   = ktb  + LL*DD;          // [L,H,R] = 204800
  float* ql   = qe   + LL*HH*RR;       // [4,L,H,3] = 49152
  float* Pb   = ql   + 4*LL*HH*3;      // [H,L,L] = 2097152; later reused as FFN hidden

  // 1. LN1
  ln_kernel<<<LL, 256, 0, stream>>>(x, ln1_g, ln1_b, ybuf);
  // 2-4. QKV projections
  dim3 gq(DD/64, LL/32);
  gemm_nt<<<gq, 256, 0, stream>>>(ybuf, Wq, bq, nullptr, qb, LL, DD, DD, 0);
  gemm_nt<<<gq, 256, 0, stream>>>(ybuf, Wk, bk, nullptr, kb, LL, DD, DD, 0);
  gemm_nt<<<gq, 256, 0, stream>>>(ybuf, Wv, bv, nullptr, vb, LL, DD, DD, 0);
  // 5. transpose k
  transpose_k<<<(LL*DD)/256, 256, 0, stream>>>(kb, ktb);
  // 6. qe table
  qe_kernel<<<dim3(LL, HH), 64, 0, stream>>>(qb, embk, qe);
  // 7. ql tables
  ql_kernel<<<(4*LL*HH*3 + 255)/256, 256, 0, stream>>>(qb, lqc_k, lqt_k, lcq_k, ltq_k, ql);
  // 8. scores + softmax
  scores_kernel<<<dim3(LL, HH), 512, 0, stream>>>(qb, ktb, qe, ql, qcr, cqr, qtr, tqr,
                                                  ct, pred, mask, Pb);
  // 9. attention out (P@v + factorized P@rel_v) -> obuf (= ybuf reused)
  attnout_kernel<<<dim3(LL, HH), 128, 0, stream>>>(Pb, vb, embv, lqc_v, lcq_v, lqt_v, ltq_v,
                                                   qcr, cqr, qtr, tqr, ct, pred, ybuf);
  // 10. output projection + residual -> d_out (= h)
  gemm_nt<<<gq, 256, 0, stream>>>(ybuf, Wo, bo, x, out, LL, DD, DD, 0);
  // 11. LN2 -> y2 (reuse qb)
  ln_kernel<<<LL, 256, 0, stream>>>(out, ln2_g, ln2_b, qb);
  // 12. FFN1 (relu) -> hidden (reuse Pb)
  gemm_nt<<<dim3(FFF/64, LL/32), 256, 0, stream>>>(qb, W1, b1, nullptr, Pb, LL, FFF, DD, 1);
  // 13. FFN2 + residual -> d_out
  gemm_nt<<<gq, 256, 0, stream>>>(Pb, W2, b2, out, out, LL, DD, FFF, 0);
}

// Round 2
// 391.975 us; speedup vs baseline: 2.1091x; 2.1091x over previous
//
#include <hip/hip_runtime.h>
#include <hip/hip_bf16.h>

#define LL 512
#define DD 1024
#define HH 8
#define DKK 128
#define QQ 256
#define CCC 128
#define TTT 128
#define RR 50
#define FFF 4096
#define QKVLD 3072   // row stride of fused qkv buffer

typedef __attribute__((ext_vector_type(8))) short short8;
typedef __attribute__((ext_vector_type(4))) float float4v;

__device__ __forceinline__ unsigned short f2bu(float f) {
  __hip_bfloat16 h = __float2bfloat16(f);
  unsigned short u;
  __builtin_memcpy(&u, &h, 2);
  return u;
}

#define GLOAD_LDS16(gp, lp) \
  __builtin_amdgcn_global_load_lds((const __attribute__((address_space(1))) void*)(gp), \
                                   (__attribute__((address_space(3))) void*)(lp), 16, 0, 0)

// ---------------- weight fp32->bf16 conversion (all weights, one launch) ----
// quad ranges: Wq,Wk,Wv -> wqkv | Wo -> wo | W1 -> w1 | W2 -> w2 | biases -> bqkv
__global__ __launch_bounds__(256) void conv_kernel(
    const float* __restrict__ Wq, const float* __restrict__ Wk,
    const float* __restrict__ Wv, const float* __restrict__ Wo,
    const float* __restrict__ W1, const float* __restrict__ W2,
    const float* __restrict__ bq, const float* __restrict__ bk,
    const float* __restrict__ bv,
    unsigned short* __restrict__ wqkv, unsigned short* __restrict__ wo,
    unsigned short* __restrict__ w1, unsigned short* __restrict__ w2,
    float* __restrict__ bqkv)
{
  int g = blockIdx.x * 256 + threadIdx.x;   // quad (4-float) index
  const float* src; unsigned short* dst; int off;
  if (g < 262144)        { src = Wq; dst = wqkv;           off = g; }
  else if (g < 524288)   { src = Wk; dst = wqkv + 1048576; off = g - 262144; }
  else if (g < 786432)   { src = Wv; dst = wqkv + 2097152; off = g - 524288; }
  else if (g < 1048576)  { src = Wo; dst = wo;             off = g - 786432; }
  else if (g < 2097152)  { src = W1; dst = w1;             off = g - 1048576; }
  else if (g < 3145728)  { src = W2; dst = w2;             off = g - 2097152; }
  else if (g < 3145728 + 768) {
    int q = g - 3145728;
    const float* s = (q < 256) ? bq : (q < 512) ? bk : bv;
    ((float4*)bqkv)[q] = ((const float4*)s)[q & 255];
    return;
  } else return;
  float4 v = ((const float4*)src)[off];
  ushort4 o4;
  o4.x = f2bu(v.x); o4.y = f2bu(v.y); o4.z = f2bu(v.z); o4.w = f2bu(v.w);
  ((ushort4*)dst)[off] = o4;
}

// ---------------- LayerNorm: fp32 in, bf16 out, one block per row ----------
__global__ __launch_bounds__(256) void ln_bf16_kernel(const float* __restrict__ x,
    const float* __restrict__ g, const float* __restrict__ b,
    unsigned short* __restrict__ y)
{
  int row = blockIdx.x, t = threadIdx.x;
  const float4 xv = ((const float4*)(x + row*DD))[t];
  float s  = xv.x+xv.y+xv.z+xv.w;
  float ss = xv.x*xv.x+xv.y*xv.y+xv.z*xv.z+xv.w*xv.w;
  __shared__ float rs[256], rss[256];
  rs[t]=s; rss[t]=ss; __syncthreads();
  for (int st=128; st>0; st>>=1){ if (t<st){ rs[t]+=rs[t+st]; rss[t]+=rss[t+st]; } __syncthreads(); }
  float mean = rs[0] * (1.0f/DD);
  float var  = rss[0]*(1.0f/DD) - mean*mean;
  float inv  = rsqrtf(var + 1e-5f);
  float4 gv = ((const float4*)g)[t], bv = ((const float4*)b)[t];
  ushort4 ov;
  ov.x = f2bu((xv.x-mean)*inv*gv.x + bv.x);
  ov.y = f2bu((xv.y-mean)*inv*gv.y + bv.y);
  ov.z = f2bu((xv.z-mean)*inv*gv.z + bv.z);
  ov.w = f2bu((xv.w-mean)*inv*gv.w + bv.w);
  ((ushort4*)(y + row*DD))[t] = ov;
}

// ---------------- bf16 MFMA GEMM: C[M,N] = A[M,K] @ B[N,K]^T (+bias,+src,relu)
// 64x64 block tile, BK=64, 256 threads = 4 waves (2x2), wave tile 32x32.
// global_load_lds width-16 staging; XOR slot swizzle for conflict-free ds_read_b128.
template<int OUT_BF16, int RELU, int HAS_SRC>
__global__ __launch_bounds__(256) void gemm_mfma(
    const unsigned short* __restrict__ A, const unsigned short* __restrict__ B,
    const float* __restrict__ bias, const float* __restrict__ src,
    void* __restrict__ Cv, int M, int N, int K)
{
  __shared__ unsigned short As[64*64];   // [row][64 k] bf16, swizzled 16B slots
  __shared__ unsigned short Bs[64*64];
  int t = threadIdx.x;
  int w = t >> 6, l = t & 63;
  int bm = blockIdx.y * 64, bn = blockIdx.x * 64;
  int wm = (w >> 1) * 32, wn = (w & 1) * 32;

  float4v acc[2][2];
  #pragma unroll
  for (int i = 0; i < 2; ++i)
    #pragma unroll
    for (int j = 0; j < 2; ++j) acc[i][j] = (float4v){0.f, 0.f, 0.f, 0.f};

  // staging: thread t loads 16B chunk: row r = t>>3 (and r+32), LDS slot s = t&7,
  // global chunk gc = s ^ (r&7)  (note (r+32)&7 == r&7)
  int r = t >> 3, s = t & 7;
  int gc = s ^ (r & 7);
  const unsigned short* gA0 = A + (size_t)(bm + r) * K + gc * 8;
  const unsigned short* gA1 = A + (size_t)(bm + r + 32) * K + gc * 8;
  const unsigned short* gB0 = B + (size_t)(bn + r) * K + gc * 8;
  const unsigned short* gB1 = B + (size_t)(bn + r + 32) * K + gc * 8;
  char* ldsA0 = (char*)As + w * 1024;
  char* ldsA1 = (char*)As + w * 1024 + 4096;
  char* ldsB0 = (char*)Bs + w * 1024;
  char* ldsB1 = (char*)Bs + w * 1024 + 4096;

  int quad = l >> 4;
  int rowA0 = wm + (l & 15), rowA1 = rowA0 + 16;
  int rowB0 = wn + (l & 15), rowB1 = rowB0 + 16;

  for (int k0 = 0; k0 < K; k0 += 64) {
    GLOAD_LDS16(gA0 + k0, ldsA0);
    GLOAD_LDS16(gA1 + k0, ldsA1);
    GLOAD_LDS16(gB0 + k0, ldsB0);
    GLOAD_LDS16(gB1 + k0, ldsB1);
    __syncthreads();
    #pragma unroll
    for (int step = 0; step < 2; ++step) {
      int c = step * 4 + quad;
      short8 a0 = *(const short8*)((const char*)As + rowA0*128 + ((c ^ (rowA0 & 7)) * 16));
      short8 a1 = *(const short8*)((const char*)As + rowA1*128 + ((c ^ (rowA1 & 7)) * 16));
      short8 b0 = *(const short8*)((const char*)Bs + rowB0*128 + ((c ^ (rowB0 & 7)) * 16));
      short8 b1 = *(const short8*)((const char*)Bs + rowB1*128 + ((c ^ (rowB1 & 7)) * 16));
      acc[0][0] = __builtin_amdgcn_mfma_f32_16x16x32_bf16(a0, b0, acc[0][0], 0, 0, 0);
      acc[0][1] = __builtin_amdgcn_mfma_f32_16x16x32_bf16(a0, b1, acc[0][1], 0, 0, 0);
      acc[1][0] = __builtin_amdgcn_mfma_f32_16x16x32_bf16(a1, b0, acc[1][0], 0, 0, 0);
      acc[1][1] = __builtin_amdgcn_mfma_f32_16x16x32_bf16(a1, b1, acc[1][1], 0, 0, 0);
    }
    __syncthreads();
  }

  #pragma unroll
  for (int mt = 0; mt < 2; ++mt)
    #pragma unroll
    for (int nt = 0; nt < 2; ++nt)
      #pragma unroll
      for (int rg = 0; rg < 4; ++rg) {
        int row = bm + wm + mt*16 + quad*4 + rg;
        int col = bn + wn + nt*16 + (l & 15);
        float vv = acc[mt][nt][rg] + bias[col];
        if (HAS_SRC) vv += src[(size_t)row * N + col];
        if (RELU) vv = fmaxf(vv, 0.f);
        if (OUT_BF16) ((unsigned short*)Cv)[(size_t)row * N + col] = f2bu(vv);
        else          ((float*)Cv)[(size_t)row * N + col] = vv;
      }
}

// ---------------- transpose k -> kt[h][d][j] (from fused qkv) ----------------
__global__ __launch_bounds__(256) void transpose_k(const float* __restrict__ qkv,
                                                   float* __restrict__ kt)
{
  int g = blockIdx.x*256 + threadIdx.x;      // 512*1024 total
  int j = g & 511; int d = (g >> 9) & 127; int h = g >> 16;
  kt[g] = qkv[j*QKVLD + DD + h*DKK + d];
}

// ---------------- qe[i,h,r] = q[i,h,:] . emb_k[r,:] ----------------
__global__ __launch_bounds__(64) void qe_kernel(const float* __restrict__ qkv,
    const float* __restrict__ embk, float* __restrict__ qe)
{
  int i = blockIdx.x, h = blockIdx.y, t = threadIdx.x;
  __shared__ float qrow[128];
  qrow[t]    = qkv[i*QKVLD + h*DKK + t];
  qrow[t+64] = qkv[i*QKVLD + h*DKK + t + 64];
  __syncthreads();
  if (t < RR) {
    float s = 0.f;
    #pragma unroll 8
    for (int d=0; d<128; ++d) s += qrow[d]*embk[t*128+d];
    qe[(i*HH+h)*RR + t] = s;
  }
}

// ---------------- ql[tb][i][h][f] = q[i,h,:] . ltab[f,:] ----------------
__global__ __launch_bounds__(256) void ql_kernel(const float* __restrict__ qkv,
    const float* __restrict__ lqc, const float* __restrict__ lqt,
    const float* __restrict__ lcq, const float* __restrict__ ltq,
    float* __restrict__ ql)
{
  int g = blockIdx.x*256 + threadIdx.x;      // 4*512*8*3 = 49152
  if (g >= 4*LL*HH*3) return;
  int f = g % 3; int h = (g/3) & 7; int i = (g/24) & 511; int tb = g / 12288;
  const float* tab = (tb==0) ? lqc : (tb==1) ? lqt : (tb==2) ? lcq : ltq;
  const float* qr = qkv + i*QKVLD + h*DKK;
  const float* tr = tab + f*128;
  float s = 0.f;
  #pragma unroll 8
  for (int d=0; d<128; ++d) s += qr[d]*tr[d];
  ql[g] = s;
}

// ---------------- scores + softmax: one block per (i,h), 512 threads -------
__global__ __launch_bounds__(512) void scores_kernel(
    const float* __restrict__ qkv,  const float* __restrict__ kt,
    const float* __restrict__ qe, const float* __restrict__ ql,
    const float* __restrict__ qcr, const float* __restrict__ cqr,
    const float* __restrict__ qtr, const float* __restrict__ tqr,
    const int* __restrict__ ct,   const int* __restrict__ pred,
    const int* __restrict__ mask, float* __restrict__ P)
{
  int i = blockIdx.x, h = blockIdx.y, j = threadIdx.x;
  __shared__ float qrow[128];
  __shared__ float qerow[52];
  __shared__ float red[512];
  if (j < 128) qrow[j] = qkv[i*QKVLD + h*DKK + j];
  if (j >= 128 && j < 128+RR) qerow[j-128] = qe[(i*HH+h)*RR + (j-128)];
  __syncthreads();

  float lq1[3] = {0,0,0}, lq2[3] = {0,0,0};
  if (i < QQ) {
    #pragma unroll
    for (int f=0; f<3; ++f) {
      lq1[f] = ql[((0*LL + i)*HH + h)*3 + f];   // qc
      lq2[f] = ql[((1*LL + i)*HH + h)*3 + f];   // qt
    }
  } else if (i < QQ+CCC) {
    #pragma unroll
    for (int f=0; f<3; ++f) lq1[f] = ql[((2*LL + i)*HH + h)*3 + f]; // cq
  } else {
    #pragma unroll
    for (int f=0; f<3; ++f) lq1[f] = ql[((3*LL + i)*HH + h)*3 + f]; // tq
  }

  float s = 0.f;
  const float* kcol = kt + (h*DKK)*LL + j;
  #pragma unroll 8
  for (int d=0; d<128; ++d) s += qrow[d]*kcol[d*LL];

  s += qerow[pred[i*LL + j]];
  if (i < QQ) {
    if (j < QQ) s += qerow[0];
    else if (j < QQ+CCC) { const float* r = qcr + (i*CCC + (j-QQ))*3;
      s += r[0]*lq1[0]+r[1]*lq1[1]+r[2]*lq1[2]; }
    else { const float* r = qtr + (i*TTT + (j-QQ-CCC))*3;
      s += r[0]*lq2[0]+r[1]*lq2[1]+r[2]*lq2[2]; }
  } else {
    if (j < QQ) {
      const float* r = (i < QQ+CCC) ? cqr + ((i-QQ)*QQ + j)*3
                                    : tqr + ((i-QQ-CCC)*QQ + j)*3;
      s += r[0]*lq1[0]+r[1]*lq1[1]+r[2]*lq1[2];
    } else {
      s += qerow[ct[(i-QQ)*(CCC+TTT) + (j-QQ)]];
    }
  }
  s *= 0.08838834764831845f;   // 1/sqrt(128)
  if (mask[i*LL + j] == 0) s = -1e9f;

  red[j] = s; __syncthreads();
  for (int st=256; st>0; st>>=1){ if (j<st) red[j]=fmaxf(red[j],red[j+st]); __syncthreads(); }
  float mx = red[0]; __syncthreads();
  float e = __expf(s - mx);
  red[j] = e; __syncthreads();
  for (int st=256; st>0; st>>=1){ if (j<st) red[j]+=red[j+st]; __syncthreads(); }
  float inv = 1.0f/red[0];
  P[((size_t)h*LL + i)*LL + j] = e*inv;
}

// ---------------- attention output: P@v + P@rel_v (factorized), bf16 out ---
__global__ __launch_bounds__(128) void attnout_kernel(
    const float* __restrict__ P,    const float* __restrict__ qkv,
    const float* __restrict__ embv,
    const float* __restrict__ lqc_v, const float* __restrict__ lcq_v,
    const float* __restrict__ lqt_v, const float* __restrict__ ltq_v,
    const float* __restrict__ qcr,  const float* __restrict__ cqr,
    const float* __restrict__ qtr,  const float* __restrict__ tqr,
    const int* __restrict__ ct,    const int* __restrict__ pred,
    unsigned short* __restrict__ obuf)
{
  int i = blockIdx.x, h = blockIdx.y, t = threadIdx.x;  // 128 threads
  __shared__ float pr[512];
  __shared__ float pw[52];
  __shared__ float pf1[3], pf2[3];
  const float* Prow = P + ((size_t)h*LL + i)*LL;
  for (int j=t; j<LL; j+=128) pr[j] = Prow[j];
  if (t < 52) pw[t] = 0.f;
  if (t < 3) { pf1[t]=0.f; pf2[t]=0.f; }
  __syncthreads();

  float lpw0 = 0.f, l1[3] = {0,0,0}, l2[3] = {0,0,0};
  for (int j=t; j<LL; j+=128) {
    float p = pr[j];
    atomicAdd(&pw[pred[i*LL + j]], p);
    if (i < QQ) {
      if (j < QQ) lpw0 += p;
      else if (j < QQ+CCC) { const float* r = qcr + (i*CCC + (j-QQ))*3;
        l1[0]+=p*r[0]; l1[1]+=p*r[1]; l1[2]+=p*r[2]; }
      else { const float* r = qtr + (i*TTT + (j-QQ-CCC))*3;
        l2[0]+=p*r[0]; l2[1]+=p*r[1]; l2[2]+=p*r[2]; }
    } else {
      if (j < QQ) {
        const float* r = (i < QQ+CCC) ? cqr + ((i-QQ)*QQ + j)*3
                                      : tqr + ((i-QQ-CCC)*QQ + j)*3;
        l1[0]+=p*r[0]; l1[1]+=p*r[1]; l1[2]+=p*r[2];
      } else {
        atomicAdd(&pw[ct[(i-QQ)*(CCC+TTT) + (j-QQ)]], p);
      }
    }
  }
  if (i < QQ) atomicAdd(&pw[0], lpw0);
  atomicAdd(&pf1[0], l1[0]); atomicAdd(&pf1[1], l1[1]); atomicAdd(&pf1[2], l1[2]);
  atomicAdd(&pf2[0], l2[0]); atomicAdd(&pf2[1], l2[1]); atomicAdd(&pf2[2], l2[2]);
  __syncthreads();

  const float* tab1; const float* tab2 = nullptr;
  if (i < QQ)          { tab1 = lqc_v; tab2 = lqt_v; }
  else if (i < QQ+CCC) { tab1 = lcq_v; }
  else                 { tab1 = ltq_v; }

  float acc = 0.f;
  const float* vcol = qkv + 2*DD + h*DKK + t;
  #pragma unroll 4
  for (int j=0; j<LL; ++j) acc += pr[j]*vcol[(size_t)j*QKVLD];
  #pragma unroll 2
  for (int r=0; r<RR; ++r) acc += pw[r]*embv[r*128 + t];
  acc += pf1[0]*tab1[t] + pf1[1]*tab1[128+t] + pf1[2]*tab1[256+t];
  if (tab2) acc += pf2[0]*tab2[t] + pf2[1]*tab2[128+t] + pf2[2]*tab2[256+t];
  obuf[i*DD + h*DKK + t] = f2bu(acc);
}

// ---------------- launch ----------------
extern "C" void kernel_launch(void* const* d_in, const int* in_sizes, int n_in,
                              void* d_out, int out_size, void* d_ws, size_t ws_size,
                              hipStream_t stream)
{
  const float* x    = (const float*)d_in[0];
  const float* qcr  = (const float*)d_in[1];
  const float* cqr  = (const float*)d_in[2];
  const float* qtr  = (const float*)d_in[3];
  const float* tqr  = (const float*)d_in[4];
  const int*   ct   = (const int*)d_in[5];
  const int*   pred = (const int*)d_in[6];
  const int*   mask = (const int*)d_in[7];
  const float* embk = (const float*)d_in[8];
  const float* embv = (const float*)d_in[9];
  const float* lqc_k = (const float*)d_in[10];
  const float* lqc_v = (const float*)d_in[11];
  const float* lcq_k = (const float*)d_in[12];
  const float* lcq_v = (const float*)d_in[13];
  const float* lqt_k = (const float*)d_in[14];
  const float* lqt_v = (const float*)d_in[15];
  const float* ltq_k = (const float*)d_in[16];
  const float* ltq_v = (const float*)d_in[17];
  const float* Wq = (const float*)d_in[18]; const float* bq = (const float*)d_in[19];
  const float* Wk = (const float*)d_in[20]; const float* bk = (const float*)d_in[21];
  const float* Wv = (const float*)d_in[22]; const float* bv = (const float*)d_in[23];
  const float* Wo = (const float*)d_in[24]; const float* bo = (const float*)d_in[25];
  const float* ln1_g = (const float*)d_in[26]; const float* ln1_b = (const float*)d_in[27];
  const float* ln2_g = (const float*)d_in[28]; const float* ln2_b = (const float*)d_in[29];
  const float* W1 = (const float*)d_in[30]; const float* b1 = (const float*)d_in[31];
  const float* W2 = (const float*)d_in[32]; const float* b2 = (const float*)d_in[33];
  float* out = (float*)d_out;

  float* wsf = (float*)d_ws;
  float* qkv  = wsf;                       // [L,3072] fp32
  float* ktb  = qkv + LL*QKVLD;            // [H,DK,L] fp32 (524288)
  float* qe   = ktb + LL*DD;               // [L,H,R]  (204800)
  float* ql   = qe  + LL*HH*RR;            // [4,L,H,3] (49152)
  float* Pb   = ql  + 4*LL*HH*3;           // [H,L,L] fp32 (2097152)
  float* bqkv = Pb  + (size_t)HH*LL*LL;    // [3072]
  unsigned short* ub = (unsigned short*)(bqkv + QKVLD);
  unsigned short* ybuf_b   = ub;                       // [L,D] bf16 (ln1/ln2 out)
  unsigned short* obuf_b   = ybuf_b + LL*DD;           // [L,D] bf16 attn out
  unsigned short* wqkv_b   = obuf_b + LL*DD;           // [3072,1024] bf16
  unsigned short* wo_b     = wqkv_b + QKVLD*DD;        // [1024,1024]
  unsigned short* w1_b     = wo_b + DD*DD;             // [4096,1024]
  unsigned short* w2_b     = w1_b + FFF*DD;            // [1024,4096]
  // hidden bf16 [L,FFF] aliases Pb (P fully consumed by attnout before FFN1)
  unsigned short* hidden_b = (unsigned short*)Pb;

  // 1. weight conversion (fp32->bf16) + bias fuse
  conv_kernel<<<(3145728 + 768 + 255)/256, 256, 0, stream>>>(
      Wq, Wk, Wv, Wo, W1, W2, bq, bk, bv, wqkv_b, wo_b, w1_b, w2_b, bqkv);
  // 2. LN1 -> bf16
  ln_bf16_kernel<<<LL, 256, 0, stream>>>(x, ln1_g, ln1_b, ybuf_b);
  // 3. fused QKV GEMM -> qkv fp32
  gemm_mfma<0,0,0><<<dim3(QKVLD/64, LL/64), 256, 0, stream>>>(
      ybuf_b, wqkv_b, bqkv, nullptr, qkv, LL, QKVLD, DD);
  // 4. transpose k
  transpose_k<<<(LL*DD)/256, 256, 0, stream>>>(qkv, ktb);
  // 5. qe table
  qe_kernel<<<dim3(LL, HH), 64, 0, stream>>>(qkv, embk, qe);
  // 6. ql tables
  ql_kernel<<<(4*LL*HH*3 + 255)/256, 256, 0, stream>>>(qkv, lqc_k, lqt_k, lcq_k, ltq_k, ql);
  // 7. scores + softmax
  scores_kernel<<<dim3(LL, HH), 512, 0, stream>>>(qkv, ktb, qe, ql, qcr, cqr, qtr, tqr,
                                                  ct, pred, mask, Pb);
  // 8. attention out -> bf16
  attnout_kernel<<<dim3(LL, HH), 128, 0, stream>>>(Pb, qkv, embv, lqc_v, lcq_v, lqt_v, ltq_v,
                                                   qcr, cqr, qtr, tqr, ct, pred, obuf_b);
  // 9. out-proj + residual(x) -> d_out (= h)
  gemm_mfma<0,0,1><<<dim3(DD/64, LL/64), 256, 0, stream>>>(
      obuf_b, wo_b, bo, x, out, LL, DD, DD);
  // 10. LN2 -> bf16
  ln_bf16_kernel<<<LL, 256, 0, stream>>>(out, ln2_g, ln2_b, ybuf_b);
  // 11. FFN1 (relu, bf16 out) -> hidden
  gemm_mfma<1,1,0><<<dim3(FFF/64, LL/64), 256, 0, stream>>>(
      ybuf_b, w1_b, b1, nullptr, hidden_b, LL, FFF, DD);
  // 12. FFN2 + residual(h) -> d_out
  gemm_mfma<0,0,1><<<dim3(DD/64, LL/64), 256, 0, stream>>>(
      hidden_b, w2_b, b2, out, out, LL, DD, FFF);
}

// Round 3
// 308.385 us; speedup vs baseline: 2.6808x; 1.2711x over previous
//
#include <hip/hip_runtime.h>
#include <hip/hip_bf16.h>

#define LL 512
#define DD 1024
#define HH 8
#define DKK 128
#define QQ 256
#define CCC 128
#define TTT 128
#define RR 50
#define FFF 4096

typedef __attribute__((ext_vector_type(8))) short short8;
typedef __attribute__((ext_vector_type(4))) float float4v;

__device__ __forceinline__ unsigned short f2bu(float f) {
  __hip_bfloat16 h = __float2bfloat16(f);
  unsigned short u; __builtin_memcpy(&u, &h, 2); return u;
}
__device__ __forceinline__ float b2f(unsigned short u) {
  unsigned int v = ((unsigned int)u) << 16;
  float f; __builtin_memcpy(&f, &v, 4); return f;
}

#define GLOAD_LDS16(gp, lp) \
  __builtin_amdgcn_global_load_lds((const __attribute__((address_space(1))) void*)(gp), \
                                   (__attribute__((address_space(3))) void*)(lp), 16, 0, 0)

// ---------------- weight fp32->bf16 conversion ----------------
__global__ __launch_bounds__(256) void conv_kernel(
    const float* __restrict__ Wq, const float* __restrict__ Wk,
    const float* __restrict__ Wv, const float* __restrict__ Wo,
    const float* __restrict__ W1, const float* __restrict__ W2,
    const float* __restrict__ bq, const float* __restrict__ bk,
    const float* __restrict__ bv,
    unsigned short* __restrict__ wqkv, unsigned short* __restrict__ wo,
    unsigned short* __restrict__ w1, unsigned short* __restrict__ w2,
    float* __restrict__ bqkv)
{
  int g = blockIdx.x * 256 + threadIdx.x;   // quad (4-float) index
  const float* src; unsigned short* dst; int off;
  if (g < 262144)        { src = Wq; dst = wqkv;           off = g; }
  else if (g < 524288)   { src = Wk; dst = wqkv + 1048576; off = g - 262144; }
  else if (g < 786432)   { src = Wv; dst = wqkv + 2097152; off = g - 524288; }
  else if (g < 1048576)  { src = Wo; dst = wo;             off = g - 786432; }
  else if (g < 2097152)  { src = W1; dst = w1;             off = g - 1048576; }
  else if (g < 3145728)  { src = W2; dst = w2;             off = g - 2097152; }
  else if (g < 3145728 + 768) {
    int q = g - 3145728;
    const float* s = (q < 256) ? bq : (q < 512) ? bk : bv;
    ((float4*)bqkv)[q] = ((const float4*)s)[q & 255];
    return;
  } else return;
  float4 v = ((const float4*)src)[off];
  ushort4 o4;
  o4.x = f2bu(v.x); o4.y = f2bu(v.y); o4.z = f2bu(v.z); o4.w = f2bu(v.w);
  ((ushort4*)dst)[off] = o4;
}

// ---------------- LayerNorm: fp32 in, bf16 out ----------------
__global__ __launch_bounds__(256) void ln_bf16_kernel(const float* __restrict__ x,
    const float* __restrict__ g, const float* __restrict__ b,
    unsigned short* __restrict__ y)
{
  int row = blockIdx.x, t = threadIdx.x;
  const float4 xv = ((const float4*)(x + row*DD))[t];
  float s  = xv.x+xv.y+xv.z+xv.w;
  float ss = xv.x*xv.x+xv.y*xv.y+xv.z*xv.z+xv.w*xv.w;
  __shared__ float rs[256], rss[256];
  rs[t]=s; rss[t]=ss; __syncthreads();
  for (int st=128; st>0; st>>=1){ if (t<st){ rs[t]+=rs[t+st]; rss[t]+=rss[t+st]; } __syncthreads(); }
  float mean = rs[0] * (1.0f/DD);
  float var  = rss[0]*(1.0f/DD) - mean*mean;
  float inv  = rsqrtf(var + 1e-5f);
  float4 gv = ((const float4*)g)[t], bv = ((const float4*)b)[t];
  ushort4 ov;
  ov.x = f2bu((xv.x-mean)*inv*gv.x + bv.x);
  ov.y = f2bu((xv.y-mean)*inv*gv.y + bv.y);
  ov.z = f2bu((xv.z-mean)*inv*gv.z + bv.z);
  ov.w = f2bu((xv.w-mean)*inv*gv.w + bv.w);
  ((ushort4*)(y + row*DD))[t] = ov;
}

// ---------------- generic bf16 MFMA GEMM ----------------
// C[z][M,N] = A[z][M,K](lda) @ B[z][N,K](ldb)^T (+bias col, +src, relu)
// 64x64 tile, BK=64, 256 thr = 4 waves 2x2, wave tile 32x32, XOR-swizzled LDS.
template<int OUT_BF16, int RELU, int HAS_SRC, int HAS_BIAS>
__global__ __launch_bounds__(256) void gemm_mfma(
    const unsigned short* __restrict__ A, int lda, size_t sAz,
    const unsigned short* __restrict__ B, int ldb, size_t sBz,
    const float* __restrict__ bias,
    const float* __restrict__ src, int ldsrc, size_t sSz,
    void* __restrict__ Cv, int ldc, size_t sCz,
    int K)
{
  __shared__ unsigned short As[64*64];
  __shared__ unsigned short Bs[64*64];
  int t = threadIdx.x;
  size_t z = blockIdx.z;
  const unsigned short* Az = A + z * sAz;
  const unsigned short* Bz = B + z * sBz;
  int w = t >> 6, l = t & 63;
  int bm = blockIdx.y * 64, bn = blockIdx.x * 64;
  int wm = (w >> 1) * 32, wn = (w & 1) * 32;

  float4v acc[2][2];
  #pragma unroll
  for (int i = 0; i < 2; ++i)
    #pragma unroll
    for (int j = 0; j < 2; ++j) acc[i][j] = (float4v){0.f, 0.f, 0.f, 0.f};

  int r = t >> 3, s = t & 7;
  int gc = s ^ (r & 7);
  const unsigned short* gA0 = Az + (size_t)(bm + r) * lda + gc * 8;
  const unsigned short* gA1 = Az + (size_t)(bm + r + 32) * lda + gc * 8;
  const unsigned short* gB0 = Bz + (size_t)(bn + r) * ldb + gc * 8;
  const unsigned short* gB1 = Bz + (size_t)(bn + r + 32) * ldb + gc * 8;
  char* ldsA0 = (char*)As + w * 1024;
  char* ldsA1 = (char*)As + w * 1024 + 4096;
  char* ldsB0 = (char*)Bs + w * 1024;
  char* ldsB1 = (char*)Bs + w * 1024 + 4096;

  int quad = l >> 4;
  int rowA0 = wm + (l & 15), rowA1 = rowA0 + 16;
  int rowB0 = wn + (l & 15), rowB1 = rowB0 + 16;

  for (int k0 = 0; k0 < K; k0 += 64) {
    GLOAD_LDS16(gA0 + k0, ldsA0);
    GLOAD_LDS16(gA1 + k0, ldsA1);
    GLOAD_LDS16(gB0 + k0, ldsB0);
    GLOAD_LDS16(gB1 + k0, ldsB1);
    __syncthreads();
    #pragma unroll
    for (int step = 0; step < 2; ++step) {
      int c = step * 4 + quad;
      short8 a0 = *(const short8*)((const char*)As + rowA0*128 + ((c ^ (rowA0 & 7)) * 16));
      short8 a1 = *(const short8*)((const char*)As + rowA1*128 + ((c ^ (rowA1 & 7)) * 16));
      short8 b0 = *(const short8*)((const char*)Bs + rowB0*128 + ((c ^ (rowB0 & 7)) * 16));
      short8 b1 = *(const short8*)((const char*)Bs + rowB1*128 + ((c ^ (rowB1 & 7)) * 16));
      acc[0][0] = __builtin_amdgcn_mfma_f32_16x16x32_bf16(a0, b0, acc[0][0], 0, 0, 0);
      acc[0][1] = __builtin_amdgcn_mfma_f32_16x16x32_bf16(a0, b1, acc[0][1], 0, 0, 0);
      acc[1][0] = __builtin_amdgcn_mfma_f32_16x16x32_bf16(a1, b0, acc[1][0], 0, 0, 0);
      acc[1][1] = __builtin_amdgcn_mfma_f32_16x16x32_bf16(a1, b1, acc[1][1], 0, 0, 0);
    }
    __syncthreads();
  }

  #pragma unroll
  for (int mt = 0; mt < 2; ++mt)
    #pragma unroll
    for (int nt = 0; nt < 2; ++nt)
      #pragma unroll
      for (int rg = 0; rg < 4; ++rg) {
        int row = bm + wm + mt*16 + quad*4 + rg;
        int col = bn + wn + nt*16 + (l & 15);
        float vv = acc[mt][nt][rg];
        if (HAS_BIAS) vv += bias[col];
        if (HAS_SRC)  vv += src[z*sSz + (size_t)row*ldsrc + col];
        if (RELU) vv = fmaxf(vv, 0.f);
        if (OUT_BF16) ((unsigned short*)Cv)[z*sCz + (size_t)row*ldc + col] = f2bu(vv);
        else          ((float*)Cv)[z*sCz + (size_t)row*ldc + col] = vv;
      }
}

// ---------------- QKV GEMM with head-scatter epilogue ----------------
// C row=i, col n in [0,3072): writes Qh[h][i][d], Kh[h][i][d], Vt[h][d][i] bf16
__global__ __launch_bounds__(256) void gemm_qkv(
    const unsigned short* __restrict__ A, const unsigned short* __restrict__ B,
    const float* __restrict__ bqkv,
    unsigned short* __restrict__ Qh, unsigned short* __restrict__ Kh,
    unsigned short* __restrict__ Vt)
{
  __shared__ unsigned short As[64*64];
  __shared__ unsigned short Bs[64*64];
  int t = threadIdx.x;
  int w = t >> 6, l = t & 63;
  int bm = blockIdx.y * 64, bn = blockIdx.x * 64;
  int wm = (w >> 1) * 32, wn = (w & 1) * 32;
  const int K = DD;

  float4v acc[2][2];
  #pragma unroll
  for (int i = 0; i < 2; ++i)
    #pragma unroll
    for (int j = 0; j < 2; ++j) acc[i][j] = (float4v){0.f, 0.f, 0.f, 0.f};

  int r = t >> 3, s = t & 7;
  int gc = s ^ (r & 7);
  const unsigned short* gA0 = A + (size_t)(bm + r) * K + gc * 8;
  const unsigned short* gA1 = A + (size_t)(bm + r + 32) * K + gc * 8;
  const unsigned short* gB0 = B + (size_t)(bn + r) * K + gc * 8;
  const unsigned short* gB1 = B + (size_t)(bn + r + 32) * K + gc * 8;
  char* ldsA0 = (char*)As + w * 1024;
  char* ldsA1 = (char*)As + w * 1024 + 4096;
  char* ldsB0 = (char*)Bs + w * 1024;
  char* ldsB1 = (char*)Bs + w * 1024 + 4096;

  int quad = l >> 4;
  int rowA0 = wm + (l & 15), rowA1 = rowA0 + 16;
  int rowB0 = wn + (l & 15), rowB1 = rowB0 + 16;

  for (int k0 = 0; k0 < K; k0 += 64) {
    GLOAD_LDS16(gA0 + k0, ldsA0);
    GLOAD_LDS16(gA1 + k0, ldsA1);
    GLOAD_LDS16(gB0 + k0, ldsB0);
    GLOAD_LDS16(gB1 + k0, ldsB1);
    __syncthreads();
    #pragma unroll
    for (int step = 0; step < 2; ++step) {
      int c = step * 4 + quad;
      short8 a0 = *(const short8*)((const char*)As + rowA0*128 + ((c ^ (rowA0 & 7)) * 16));
      short8 a1 = *(const short8*)((const char*)As + rowA1*128 + ((c ^ (rowA1 & 7)) * 16));
      short8 b0 = *(const short8*)((const char*)Bs + rowB0*128 + ((c ^ (rowB0 & 7)) * 16));
      short8 b1 = *(const short8*)((const char*)Bs + rowB1*128 + ((c ^ (rowB1 & 7)) * 16));
      acc[0][0] = __builtin_amdgcn_mfma_f32_16x16x32_bf16(a0, b0, acc[0][0], 0, 0, 0);
      acc[0][1] = __builtin_amdgcn_mfma_f32_16x16x32_bf16(a0, b1, acc[0][1], 0, 0, 0);
      acc[1][0] = __builtin_amdgcn_mfma_f32_16x16x32_bf16(a1, b0, acc[1][0], 0, 0, 0);
      acc[1][1] = __builtin_amdgcn_mfma_f32_16x16x32_bf16(a1, b1, acc[1][1], 0, 0, 0);
    }
    __syncthreads();
  }

  #pragma unroll
  for (int mt = 0; mt < 2; ++mt)
    #pragma unroll
    for (int nt = 0; nt < 2; ++nt)
      #pragma unroll
      for (int rg = 0; rg < 4; ++rg) {
        int row = bm + wm + mt*16 + quad*4 + rg;
        int col = bn + wn + nt*16 + (l & 15);
        float vv = acc[mt][nt][rg] + bqkv[col];
        int part = col >> 10, hh = (col >> 7) & 7, d = col & 127;
        unsigned short o = f2bu(vv);
        if (part == 0)      Qh[((size_t)hh*LL + row)*DKK + d] = o;
        else if (part == 1) Kh[((size_t)hh*LL + row)*DKK + d] = o;
        else                Vt[((size_t)hh*DKK + d)*LL + row] = o;
      }
}

// ---------------- qe[i,h,r] = q[i,h,:].emb_k[r,:] ----------------
__global__ __launch_bounds__(64) void qe_kernel(const unsigned short* __restrict__ Qh,
    const float* __restrict__ embk, float* __restrict__ qe)
{
  int i = blockIdx.x, h = blockIdx.y, t = threadIdx.x;
  __shared__ float qrow[128];
  const unsigned short* qp = Qh + ((size_t)h*LL + i)*DKK;
  qrow[t] = b2f(qp[t]); qrow[t+64] = b2f(qp[t+64]);
  __syncthreads();
  if (t < RR) {
    float s = 0.f;
    #pragma unroll 8
    for (int d=0; d<128; ++d) s += qrow[d]*embk[t*128+d];
    qe[(i*HH+h)*RR + t] = s;
  }
}

// ---------------- ql[tb][i][h][f] = q[i,h,:].ltab[f,:] ----------------
__global__ __launch_bounds__(256) void ql_kernel(const unsigned short* __restrict__ Qh,
    const float* __restrict__ lqc, const float* __restrict__ lqt,
    const float* __restrict__ lcq, const float* __restrict__ ltq,
    float* __restrict__ ql)
{
  int g = blockIdx.x*256 + threadIdx.x;
  if (g >= 4*LL*HH*3) return;
  int f = g % 3; int h = (g/3) & 7; int i = (g/24) & 511; int tb = g / 12288;
  const float* tab = (tb==0) ? lqc : (tb==1) ? lqt : (tb==2) ? lcq : ltq;
  const unsigned short* qr = Qh + ((size_t)h*LL + i)*DKK;
  const float* tr = tab + f*128;
  float s = 0.f;
  #pragma unroll 8
  for (int d=0; d<128; ++d) s += b2f(qr[d])*tr[d];
  ql[g] = s;
}

// ---------------- bias + mask + softmax, in-place S -> P bf16 ----------------
__global__ __launch_bounds__(512) void softmax_kernel(
    float* __restrict__ S,
    const float* __restrict__ qe, const float* __restrict__ ql,
    const float* __restrict__ qcr, const float* __restrict__ cqr,
    const float* __restrict__ qtr, const float* __restrict__ tqr,
    const int* __restrict__ ct,   const int* __restrict__ pred,
    const int* __restrict__ mask)
{
  int i = blockIdx.x, h = blockIdx.y, j = threadIdx.x;
  __shared__ float qerow[52];
  __shared__ float red[512];
  if (j < RR) qerow[j] = qe[(i*HH+h)*RR + j];
  __syncthreads();

  float lq1[3] = {0,0,0}, lq2[3] = {0,0,0};
  if (i < QQ) {
    #pragma unroll
    for (int f=0; f<3; ++f) {
      lq1[f] = ql[((0*LL + i)*HH + h)*3 + f];
      lq2[f] = ql[((1*LL + i)*HH + h)*3 + f];
    }
  } else if (i < QQ+CCC) {
    #pragma unroll
    for (int f=0; f<3; ++f) lq1[f] = ql[((2*LL + i)*HH + h)*3 + f];
  } else {
    #pragma unroll
    for (int f=0; f<3; ++f) lq1[f] = ql[((3*LL + i)*HH + h)*3 + f];
  }

  float s = S[((size_t)h*LL + i)*LL + j];
  s += qerow[pred[i*LL + j]];
  if (i < QQ) {
    if (j < QQ) s += qerow[0];
    else if (j < QQ+CCC) { const float* r = qcr + (i*CCC + (j-QQ))*3;
      s += r[0]*lq1[0]+r[1]*lq1[1]+r[2]*lq1[2]; }
    else { const float* r = qtr + (i*TTT + (j-QQ-CCC))*3;
      s += r[0]*lq2[0]+r[1]*lq2[1]+r[2]*lq2[2]; }
  } else {
    if (j < QQ) {
      const float* r = (i < QQ+CCC) ? cqr + ((i-QQ)*QQ + j)*3
                                    : tqr + ((i-QQ-CCC)*QQ + j)*3;
      s += r[0]*lq1[0]+r[1]*lq1[1]+r[2]*lq1[2];
    } else {
      s += qerow[ct[(i-QQ)*(CCC+TTT) + (j-QQ)]];
    }
  }
  s *= 0.08838834764831845f;
  if (mask[i*LL + j] == 0) s = -1e9f;

  red[j] = s; __syncthreads();
  for (int st=256; st>0; st>>=1){ if (j<st) red[j]=fmaxf(red[j],red[j+st]); __syncthreads(); }
  float mx = red[0]; __syncthreads();
  float e = __expf(s - mx);
  red[j] = e; __syncthreads();
  for (int st=256; st>0; st>>=1){ if (j<st) red[j]+=red[j+st]; __syncthreads(); }
  float inv = 1.0f/red[0];
  // in-place: P bf16 row at same row start, ld = 1024 shorts
  ((unsigned short*)S)[((size_t)h*LL + i)*1024 + j] = f2bu(e*inv);
}

// ---------------- pw scatter + o2 = pw@embv + pf.tabs ----------------
// one block per row i (256 thr), all 8 heads
__global__ __launch_bounds__(256) void pw_kernel(
    const unsigned short* __restrict__ P,   // ld 1024 shorts, [h][i] rows
    const float* __restrict__ embv,
    const float* __restrict__ lqc_v, const float* __restrict__ lcq_v,
    const float* __restrict__ lqt_v, const float* __restrict__ ltq_v,
    const float* __restrict__ qcr,  const float* __restrict__ cqr,
    const float* __restrict__ qtr,  const float* __restrict__ tqr,
    const int* __restrict__ ct,    const int* __restrict__ pred,
    float* __restrict__ o2)                 // [8][512][128]
{
  int i = blockIdx.x, t = threadIdx.x;
  __shared__ float pw8[8][56];
  __shared__ float pf1s[24], pf2s[24];
  __shared__ int predrow[512];
  __shared__ int ctrow[256];
  for (int k=t; k<8*56; k+=256) ((float*)pw8)[k] = 0.f;
  if (t < 24) { pf1s[t]=0.f; pf2s[t]=0.f; }
  for (int k=t; k<512; k+=256) predrow[k] = pred[i*LL + k];
  if (i >= QQ) { if (t < 256) ctrow[t] = ct[(i-QQ)*(CCC+TTT) + t]; }
  __syncthreads();

  int h = t >> 5, lane = t & 31;
  float qq = 0.f, l1[3] = {0,0,0}, l2[3] = {0,0,0};
  const unsigned short* Prow = P + ((size_t)h*LL + i)*1024;
  for (int jj = 0; jj < 16; ++jj) {
    int j = lane + jj*32;
    float p = b2f(Prow[j]);
    atomicAdd(&pw8[h][predrow[j]], p);
    if (i < QQ) {
      if (j < QQ) qq += p;
      else if (j < QQ+CCC) { const float* r = qcr + (i*CCC + (j-QQ))*3;
        l1[0]+=p*r[0]; l1[1]+=p*r[1]; l1[2]+=p*r[2]; }
      else { const float* r = qtr + (i*TTT + (j-QQ-CCC))*3;
        l2[0]+=p*r[0]; l2[1]+=p*r[1]; l2[2]+=p*r[2]; }
    } else {
      if (j < QQ) {
        const float* r = (i < QQ+CCC) ? cqr + ((i-QQ)*QQ + j)*3
                                      : tqr + ((i-QQ-CCC)*QQ + j)*3;
        l1[0]+=p*r[0]; l1[1]+=p*r[1]; l1[2]+=p*r[2];
      } else {
        atomicAdd(&pw8[h][ctrow[j-QQ]], p);
      }
    }
  }
  if (i < QQ) atomicAdd(&pw8[h][0], qq);
  atomicAdd(&pf1s[h*3+0], l1[0]); atomicAdd(&pf1s[h*3+1], l1[1]); atomicAdd(&pf1s[h*3+2], l1[2]);
  atomicAdd(&pf2s[h*3+0], l2[0]); atomicAdd(&pf2s[h*3+1], l2[1]); atomicAdd(&pf2s[h*3+2], l2[2]);
  __syncthreads();

  const float* tab1; const float* tab2 = nullptr;
  if (i < QQ)          { tab1 = lqc_v; tab2 = lqt_v; }
  else if (i < QQ+CCC) { tab1 = lcq_v; }
  else                 { tab1 = ltq_v; }

  for (int o = t; o < 1024; o += 256) {
    int h2 = o >> 7, d = o & 127;
    float acc = 0.f;
    #pragma unroll 5
    for (int r = 0; r < RR; ++r) acc += pw8[h2][r]*embv[r*128 + d];
    acc += pf1s[h2*3+0]*tab1[d] + pf1s[h2*3+1]*tab1[128+d] + pf1s[h2*3+2]*tab1[256+d];
    if (tab2) acc += pf2s[h2*3+0]*tab2[d] + pf2s[h2*3+1]*tab2[128+d] + pf2s[h2*3+2]*tab2[256+d];
    o2[((size_t)h2*LL + i)*DKK + d] = acc;
  }
}

// ---------------- launch ----------------
extern "C" void kernel_launch(void* const* d_in, const int* in_sizes, int n_in,
                              void* d_out, int out_size, void* d_ws, size_t ws_size,
                              hipStream_t stream)
{
  const float* x    = (const float*)d_in[0];
  const float* qcr  = (const float*)d_in[1];
  const float* cqr  = (const float*)d_in[2];
  const float* qtr  = (const float*)d_in[3];
  const float* tqr  = (const float*)d_in[4];
  const int*   ct   = (const int*)d_in[5];
  const int*   pred = (const int*)d_in[6];
  const int*   mask = (const int*)d_in[7];
  const float* embk = (const float*)d_in[8];
  const float* embv = (const float*)d_in[9];
  const float* lqc_k = (const float*)d_in[10];
  const float* lqc_v = (const float*)d_in[11];
  const float* lcq_k = (const float*)d_in[12];
  const float* lcq_v = (const float*)d_in[13];
  const float* lqt_k = (const float*)d_in[14];
  const float* lqt_v = (const float*)d_in[15];
  const float* ltq_k = (const float*)d_in[16];
  const float* ltq_v = (const float*)d_in[17];
  const float* Wq = (const float*)d_in[18];
  const float* Wk = (const float*)d_in[20]; const float* bk = (const float*)d_in[21];
  const float* bq = (const float*)d_in[19];
  const float* Wv = (const float*)d_in[22]; const float* bv = (const float*)d_in[23];
  const float* Wo = (const float*)d_in[24]; const float* bo = (const float*)d_in[25];
  const float* ln1_g = (const float*)d_in[26]; const float* ln1_b = (const float*)d_in[27];
  const float* ln2_g = (const float*)d_in[28]; const float* ln2_b = (const float*)d_in[29];
  const float* W1 = (const float*)d_in[30]; const float* b1 = (const float*)d_in[31];
  const float* W2 = (const float*)d_in[32]; const float* b2 = (const float*)d_in[33];
  float* out = (float*)d_out;

  float* wsf = (float*)d_ws;
  float* S    = wsf;                       // [8][512][512] fp32; then P bf16 in-place; then hidden bf16
  float* o2   = S + (size_t)HH*LL*LL;      // [8][512][128] fp32
  float* qe   = o2 + (size_t)HH*LL*DKK;    // [L,H,R]
  float* ql   = qe + LL*HH*RR;             // [4,L,H,3]
  float* bqkv = ql + 4*LL*HH*3;            // [3072]
  unsigned short* ub = (unsigned short*)(bqkv + 3072);
  unsigned short* ybuf_b = ub;                     // [L,D]
  unsigned short* obuf_b = ybuf_b + LL*DD;         // [L,D]
  unsigned short* Qh     = obuf_b + LL*DD;         // [H][L][DK]
  unsigned short* Kh     = Qh + LL*DD;             // [H][L][DK]
  unsigned short* Vt     = Kh + LL*DD;             // [H][DK][L]
  unsigned short* wqkv_b = Vt + LL*DD;             // [3072,1024]
  unsigned short* wo_b   = wqkv_b + (size_t)3*DD*DD;
  unsigned short* w1_b   = wo_b + (size_t)DD*DD;
  unsigned short* w2_b   = w1_b + (size_t)FFF*DD;
  unsigned short* PS     = (unsigned short*)S;     // P bf16, ld 1024 shorts
  unsigned short* hidden = (unsigned short*)S;     // [L][FFF] bf16 (after P dead)

  // 1. weights -> bf16
  conv_kernel<<<(3145728 + 768 + 255)/256, 256, 0, stream>>>(
      Wq, Wk, Wv, Wo, W1, W2, bq, bk, bv, wqkv_b, wo_b, w1_b, w2_b, bqkv);
  // 2. LN1 -> bf16
  ln_bf16_kernel<<<LL, 256, 0, stream>>>(x, ln1_g, ln1_b, ybuf_b);
  // 3. QKV GEMM with head scatter
  gemm_qkv<<<dim3(48, 8), 256, 0, stream>>>(ybuf_b, wqkv_b, bqkv, Qh, Kh, Vt);
  // 4-5. relation dot tables
  qe_kernel<<<dim3(LL, HH), 64, 0, stream>>>(Qh, embk, qe);
  ql_kernel<<<(4*LL*HH*3 + 255)/256, 256, 0, stream>>>(Qh, lqc_k, lqt_k, lcq_k, ltq_k, ql);
  // 6. scores GEMM: S[h] = Qh[h] @ Kh[h]^T
  gemm_mfma<0,0,0,0><<<dim3(8, 8, 8), 256, 0, stream>>>(
      Qh, DKK, (size_t)LL*DKK, Kh, DKK, (size_t)LL*DKK,
      nullptr, nullptr, 0, 0, S, LL, (size_t)LL*LL, DKK);
  // 7. bias+mask+softmax in-place -> P bf16
  softmax_kernel<<<dim3(LL, HH), 512, 0, stream>>>(S, qe, ql, qcr, cqr, qtr, tqr,
                                                   ct, pred, mask);
  // 8. pw scatter -> o2
  pw_kernel<<<LL, 256, 0, stream>>>(PS, embv, lqc_v, lcq_v, lqt_v, ltq_v,
                                    qcr, cqr, qtr, tqr, ct, pred, o2);
  // 9. PV GEMM + o2 add -> obuf bf16
  gemm_mfma<1,0,1,0><<<dim3(2, 8, 8), 256, 0, stream>>>(
      PS, 1024, (size_t)LL*1024, Vt, LL, (size_t)DKK*LL,
      nullptr, o2, DKK, (size_t)LL*DKK, obuf_b, DD, (size_t)DKK, LL);
  // 10. out-proj + residual(x) -> out
  gemm_mfma<0,0,1,1><<<dim3(16, 8, 1), 256, 0, stream>>>(
      obuf_b, DD, 0, wo_b, DD, 0, bo, x, DD, 0, out, DD, 0, DD);
  // 11. LN2 -> bf16
  ln_bf16_kernel<<<LL, 256, 0, stream>>>(out, ln2_g, ln2_b, ybuf_b);
  // 12. FFN1 relu -> hidden bf16 (S region, P dead)
  gemm_mfma<1,1,0,1><<<dim3(64, 8, 1), 256, 0, stream>>>(
      ybuf_b, DD, 0, w1_b, DD, 0, b1, nullptr, 0, 0, hidden, FFF, 0, DD);
  // 13. FFN2 + residual -> out
  gemm_mfma<0,0,1,1><<<dim3(16, 8, 1), 256, 0, stream>>>(
      hidden, FFF, 0, w2_b, FFF, 0, b2, out, DD, 0, out, DD, 0, FFF);
}

// Round 4
// 298.464 us; speedup vs baseline: 2.7699x; 1.0332x over previous
//
#include <hip/hip_runtime.h>
#include <hip/hip_bf16.h>

#define LL 512
#define DD 1024
#define HH 8
#define DKK 128
#define QQ 256
#define CCC 128
#define TTT 128
#define RR 50
#define FFF 4096

typedef __attribute__((ext_vector_type(8))) short short8;
typedef __attribute__((ext_vector_type(4))) float float4v;

__device__ __forceinline__ unsigned short f2bu(float f) {
  __hip_bfloat16 h = __float2bfloat16(f);
  unsigned short u; __builtin_memcpy(&u, &h, 2); return u;
}
__device__ __forceinline__ float b2f(unsigned short u) {
  unsigned int v = ((unsigned int)u) << 16;
  float f; __builtin_memcpy(&f, &v, 4); return f;
}

#define GLOAD_LDS16(gp, lp) \
  __builtin_amdgcn_global_load_lds((const __attribute__((address_space(1))) void*)(gp), \
                                   (__attribute__((address_space(3))) void*)(lp), 16, 0, 0)

// ---------------- weight fp32->bf16 conversion ----------------
__global__ __launch_bounds__(256) void conv_kernel(
    const float* __restrict__ Wq, const float* __restrict__ Wk,
    const float* __restrict__ Wv, const float* __restrict__ Wo,
    const float* __restrict__ W1, const float* __restrict__ W2,
    const float* __restrict__ bq, const float* __restrict__ bk,
    const float* __restrict__ bv,
    unsigned short* __restrict__ wqkv, unsigned short* __restrict__ wo,
    unsigned short* __restrict__ w1, unsigned short* __restrict__ w2,
    float* __restrict__ bqkv)
{
  int g = blockIdx.x * 256 + threadIdx.x;   // quad (4-float) index
  const float* src; unsigned short* dst; int off;
  if (g < 262144)        { src = Wq; dst = wqkv;           off = g; }
  else if (g < 524288)   { src = Wk; dst = wqkv + 1048576; off = g - 262144; }
  else if (g < 786432)   { src = Wv; dst = wqkv + 2097152; off = g - 524288; }
  else if (g < 1048576)  { src = Wo; dst = wo;             off = g - 786432; }
  else if (g < 2097152)  { src = W1; dst = w1;             off = g - 1048576; }
  else if (g < 3145728)  { src = W2; dst = w2;             off = g - 2097152; }
  else if (g < 3145728 + 768) {
    int q = g - 3145728;
    const float* s = (q < 256) ? bq : (q < 512) ? bk : bv;
    ((float4*)bqkv)[q] = ((const float4*)s)[q & 255];
    return;
  } else return;
  float4 v = ((const float4*)src)[off];
  ushort4 o4;
  o4.x = f2bu(v.x); o4.y = f2bu(v.y); o4.z = f2bu(v.z); o4.w = f2bu(v.w);
  ((ushort4*)dst)[off] = o4;
}

// ---------------- LayerNorm: fp32 in, bf16 out ----------------
__global__ __launch_bounds__(256) void ln_bf16_kernel(const float* __restrict__ x,
    const float* __restrict__ g, const float* __restrict__ b,
    unsigned short* __restrict__ y)
{
  int row = blockIdx.x, t = threadIdx.x;
  const float4 xv = ((const float4*)(x + row*DD))[t];
  float s  = xv.x+xv.y+xv.z+xv.w;
  float ss = xv.x*xv.x+xv.y*xv.y+xv.z*xv.z+xv.w*xv.w;
  __shared__ float rs[256], rss[256];
  rs[t]=s; rss[t]=ss; __syncthreads();
  for (int st=128; st>0; st>>=1){ if (t<st){ rs[t]+=rs[t+st]; rss[t]+=rss[t+st]; } __syncthreads(); }
  float mean = rs[0] * (1.0f/DD);
  float var  = rss[0]*(1.0f/DD) - mean*mean;
  float inv  = rsqrtf(var + 1e-5f);
  float4 gv = ((const float4*)g)[t], bv = ((const float4*)b)[t];
  ushort4 ov;
  ov.x = f2bu((xv.x-mean)*inv*gv.x + bv.x);
  ov.y = f2bu((xv.y-mean)*inv*gv.y + bv.y);
  ov.z = f2bu((xv.z-mean)*inv*gv.z + bv.z);
  ov.w = f2bu((xv.w-mean)*inv*gv.w + bv.w);
  ((ushort4*)(y + row*DD))[t] = ov;
}

// ======== double-buffered bf16 MFMA GEMM ========
// C[z][M,N] = A[z][M,K](lda) @ B[z][N,K](ldb)^T (+bias,+src,relu)
// BM x BN tile, BK=64, 256 thr = 4 waves (2x2), wave tile (BM/2)x(BN/2).
// One barrier per K-iter: barrier -> prefetch(k+1) -> compute(k).
template<int BM, int BN, int OUT_BF16, int RELU, int HAS_SRC, int HAS_BIAS>
__global__ __launch_bounds__(256) void gemm_db(
    const unsigned short* __restrict__ A, int lda, size_t sAz,
    const unsigned short* __restrict__ B, int ldb, size_t sBz,
    const float* __restrict__ bias,
    const float* __restrict__ src, int ldsrc, size_t sSz,
    void* __restrict__ Cv, int ldc, size_t sCz,
    int K)
{
  constexpr int WM = BM/2, WN = BN/2;
  constexpr int FM = WM/16, FN = WN/16;
  constexpr int ABYTES = BM*128;          // 64 k * 2B per row
  constexpr int TILE = ABYTES + BN*128;
  __shared__ char lds[2*TILE];
  int t = threadIdx.x;
  size_t z = blockIdx.z;
  const unsigned short* Az = A + z*sAz;
  const unsigned short* Bz = B + z*sBz;
  int w = t >> 6, l = t & 63;
  int bm = blockIdx.y * BM, bn = blockIdx.x * BN;
  int wm = (w >> 1) * WM, wn = (w & 1) * WN;

  float4v acc[FM][FN];
  #pragma unroll
  for (int m = 0; m < FM; ++m)
    #pragma unroll
    for (int n = 0; n < FN; ++n) acc[m][n] = (float4v){0.f,0.f,0.f,0.f};

  int rl = l >> 3, sl = l & 7;
  int gc = sl ^ rl;                       // global 16B-chunk this lane fetches
  int quad = l >> 4, lrow = l & 15;

  auto issue = [&](int k0, int buf) {
    char* base = lds + buf*TILE;
    #pragma unroll
    for (int p = 0; p < BM/32; ++p) {
      const unsigned short* g = Az + (size_t)(bm + p*32 + w*8 + rl)*lda + k0 + gc*8;
      GLOAD_LDS16(g, base + (p*32 + w*8)*128);
    }
    #pragma unroll
    for (int p = 0; p < BN/32; ++p) {
      const unsigned short* g = Bz + (size_t)(bn + p*32 + w*8 + rl)*ldb + k0 + gc*8;
      GLOAD_LDS16(g, base + ABYTES + (p*32 + w*8)*128);
    }
  };

  int nit = K >> 6;
  issue(0, 0);
  for (int it = 0; it < nit; ++it) {
    __syncthreads();                       // drains vmcnt -> buf[it&1] ready
    if (it + 1 < nit) issue((it + 1) << 6, (it + 1) & 1);
    const char* ab = lds + (it & 1)*TILE;
    const char* bb = ab + ABYTES;
    #pragma unroll
    for (int step = 0; step < 2; ++step) {
      int c = step*4 + quad;
      short8 af[FM], bf[FN];
      #pragma unroll
      for (int m = 0; m < FM; ++m) {
        int R = wm + m*16 + lrow;
        af[m] = *(const short8*)(ab + R*128 + ((c ^ (R & 7))*16));
      }
      #pragma unroll
      for (int n = 0; n < FN; ++n) {
        int R = wn + n*16 + lrow;
        bf[n] = *(const short8*)(bb + R*128 + ((c ^ (R & 7))*16));
      }
      #pragma unroll
      for (int m = 0; m < FM; ++m)
        #pragma unroll
        for (int n = 0; n < FN; ++n)
          acc[m][n] = __builtin_amdgcn_mfma_f32_16x16x32_bf16(af[m], bf[n], acc[m][n], 0, 0, 0);
    }
  }

  #pragma unroll
  for (int m = 0; m < FM; ++m)
    #pragma unroll
    for (int n = 0; n < FN; ++n)
      #pragma unroll
      for (int rg = 0; rg < 4; ++rg) {
        int row = bm + wm + m*16 + quad*4 + rg;
        int col = bn + wn + n*16 + lrow;
        float vv = acc[m][n][rg];
        if (HAS_BIAS) vv += bias[col];
        if (HAS_SRC)  vv += src[z*sSz + (size_t)row*ldsrc + col];
        if (RELU) vv = fmaxf(vv, 0.f);
        if (OUT_BF16) ((unsigned short*)Cv)[z*sCz + (size_t)row*ldc + col] = f2bu(vv);
        else          ((float*)Cv)[z*sCz + (size_t)row*ldc + col] = vv;
      }
}

// ---------------- QKV GEMM (128x64, double-buffered) + head-scatter --------
__global__ __launch_bounds__(256) void gemm_qkv_db(
    const unsigned short* __restrict__ A, const unsigned short* __restrict__ B,
    const float* __restrict__ bqkv,
    unsigned short* __restrict__ Qh, unsigned short* __restrict__ Kh,
    unsigned short* __restrict__ Vt)
{
  constexpr int BM = 128, BN = 64;
  constexpr int WM = 64, WN = 32, FM = 4, FN = 2;
  constexpr int ABYTES = BM*128;
  constexpr int TILE = ABYTES + BN*128;
  __shared__ char lds[2*TILE];
  int t = threadIdx.x;
  int w = t >> 6, l = t & 63;
  int bm = blockIdx.y * BM, bn = blockIdx.x * BN;
  int wm = (w >> 1) * WM, wn = (w & 1) * WN;
  const int K = DD;

  float4v acc[FM][FN];
  #pragma unroll
  for (int m = 0; m < FM; ++m)
    #pragma unroll
    for (int n = 0; n < FN; ++n) acc[m][n] = (float4v){0.f,0.f,0.f,0.f};

  int rl = l >> 3, sl = l & 7;
  int gc = sl ^ rl;
  int quad = l >> 4, lrow = l & 15;

  auto issue = [&](int k0, int buf) {
    char* base = lds + buf*TILE;
    #pragma unroll
    for (int p = 0; p < BM/32; ++p) {
      const unsigned short* g = A + (size_t)(bm + p*32 + w*8 + rl)*K + k0 + gc*8;
      GLOAD_LDS16(g, base + (p*32 + w*8)*128);
    }
    #pragma unroll
    for (int p = 0; p < BN/32; ++p) {
      const unsigned short* g = B + (size_t)(bn + p*32 + w*8 + rl)*K + k0 + gc*8;
      GLOAD_LDS16(g, base + ABYTES + (p*32 + w*8)*128);
    }
  };

  int nit = K >> 6;
  issue(0, 0);
  for (int it = 0; it < nit; ++it) {
    __syncthreads();
    if (it + 1 < nit) issue((it + 1) << 6, (it + 1) & 1);
    const char* ab = lds + (it & 1)*TILE;
    const char* bb = ab + ABYTES;
    #pragma unroll
    for (int step = 0; step < 2; ++step) {
      int c = step*4 + quad;
      short8 af[FM], bf[FN];
      #pragma unroll
      for (int m = 0; m < FM; ++m) {
        int R = wm + m*16 + lrow;
        af[m] = *(const short8*)(ab + R*128 + ((c ^ (R & 7))*16));
      }
      #pragma unroll
      for (int n = 0; n < FN; ++n) {
        int R = wn + n*16 + lrow;
        bf[n] = *(const short8*)(bb + R*128 + ((c ^ (R & 7))*16));
      }
      #pragma unroll
      for (int m = 0; m < FM; ++m)
        #pragma unroll
        for (int n = 0; n < FN; ++n)
          acc[m][n] = __builtin_amdgcn_mfma_f32_16x16x32_bf16(af[m], bf[n], acc[m][n], 0, 0, 0);
    }
  }

  #pragma unroll
  for (int m = 0; m < FM; ++m)
    #pragma unroll
    for (int n = 0; n < FN; ++n)
      #pragma unroll
      for (int rg = 0; rg < 4; ++rg) {
        int row = bm + wm + m*16 + quad*4 + rg;
        int col = bn + wn + n*16 + lrow;
        float vv = acc[m][n][rg] + bqkv[col];
        int part = col >> 10, hh = (col >> 7) & 7, d = col & 127;
        unsigned short o = f2bu(vv);
        if (part == 0)      Qh[((size_t)hh*LL + row)*DKK + d] = o;
        else if (part == 1) Kh[((size_t)hh*LL + row)*DKK + d] = o;
        else                Vt[((size_t)hh*DKK + d)*LL + row] = o;
      }
}

// ---------------- qe[i,h,r] = q[i,h,:].emb_k[r,:] ----------------
__global__ __launch_bounds__(64) void qe_kernel(const unsigned short* __restrict__ Qh,
    const float* __restrict__ embk, float* __restrict__ qe)
{
  int i = blockIdx.x, h = blockIdx.y, t = threadIdx.x;
  __shared__ float qrow[128];
  const unsigned short* qp = Qh + ((size_t)h*LL + i)*DKK;
  qrow[t] = b2f(qp[t]); qrow[t+64] = b2f(qp[t+64]);
  __syncthreads();
  if (t < RR) {
    float s = 0.f;
    #pragma unroll 8
    for (int d=0; d<128; ++d) s += qrow[d]*embk[t*128+d];
    qe[(i*HH+h)*RR + t] = s;
  }
}

// ---------------- ql[tb][i][h][f] = q[i,h,:].ltab[f,:] ----------------
__global__ __launch_bounds__(256) void ql_kernel(const unsigned short* __restrict__ Qh,
    const float* __restrict__ lqc, const float* __restrict__ lqt,
    const float* __restrict__ lcq, const float* __restrict__ ltq,
    float* __restrict__ ql)
{
  int g = blockIdx.x*256 + threadIdx.x;
  if (g >= 4*LL*HH*3) return;
  int f = g % 3; int h = (g/3) & 7; int i = (g/24) & 511; int tb = g / 12288;
  const float* tab = (tb==0) ? lqc : (tb==1) ? lqt : (tb==2) ? lcq : ltq;
  const unsigned short* qr = Qh + ((size_t)h*LL + i)*DKK;
  const float* tr = tab + f*128;
  float s = 0.f;
  #pragma unroll 8
  for (int d=0; d<128; ++d) s += b2f(qr[d])*tr[d];
  ql[g] = s;
}

// ---------------- bias + mask + softmax, in-place S -> P bf16 ----------------
__global__ __launch_bounds__(512) void softmax_kernel(
    float* __restrict__ S,
    const float* __restrict__ qe, const float* __restrict__ ql,
    const float* __restrict__ qcr, const float* __restrict__ cqr,
    const float* __restrict__ qtr, const float* __restrict__ tqr,
    const int* __restrict__ ct,   const int* __restrict__ pred,
    const int* __restrict__ mask)
{
  int i = blockIdx.x, h = blockIdx.y, j = threadIdx.x;
  __shared__ float qerow[52];
  __shared__ float red[512];
  if (j < RR) qerow[j] = qe[(i*HH+h)*RR + j];
  __syncthreads();

  float lq1[3] = {0,0,0}, lq2[3] = {0,0,0};
  if (i < QQ) {
    #pragma unroll
    for (int f=0; f<3; ++f) {
      lq1[f] = ql[((0*LL + i)*HH + h)*3 + f];
      lq2[f] = ql[((1*LL + i)*HH + h)*3 + f];
    }
  } else if (i < QQ+CCC) {
    #pragma unroll
    for (int f=0; f<3; ++f) lq1[f] = ql[((2*LL + i)*HH + h)*3 + f];
  } else {
    #pragma unroll
    for (int f=0; f<3; ++f) lq1[f] = ql[((3*LL + i)*HH + h)*3 + f];
  }

  float s = S[((size_t)h*LL + i)*LL + j];
  s += qerow[pred[i*LL + j]];
  if (i < QQ) {
    if (j < QQ) s += qerow[0];
    else if (j < QQ+CCC) { const float* r = qcr + (i*CCC + (j-QQ))*3;
      s += r[0]*lq1[0]+r[1]*lq1[1]+r[2]*lq1[2]; }
    else { const float* r = qtr + (i*TTT + (j-QQ-CCC))*3;
      s += r[0]*lq2[0]+r[1]*lq2[1]+r[2]*lq2[2]; }
  } else {
    if (j < QQ) {
      const float* r = (i < QQ+CCC) ? cqr + ((i-QQ)*QQ + j)*3
                                    : tqr + ((i-QQ-CCC)*QQ + j)*3;
      s += r[0]*lq1[0]+r[1]*lq1[1]+r[2]*lq1[2];
    } else {
      s += qerow[ct[(i-QQ)*(CCC+TTT) + (j-QQ)]];
    }
  }
  s *= 0.08838834764831845f;
  if (mask[i*LL + j] == 0) s = -1e9f;

  red[j] = s; __syncthreads();
  for (int st=256; st>0; st>>=1){ if (j<st) red[j]=fmaxf(red[j],red[j+st]); __syncthreads(); }
  float mx = red[0]; __syncthreads();
  float e = __expf(s - mx);
  red[j] = e; __syncthreads();
  for (int st=256; st>0; st>>=1){ if (j<st) red[j]+=red[j+st]; __syncthreads(); }
  float inv = 1.0f/red[0];
  ((unsigned short*)S)[((size_t)h*LL + i)*1024 + j] = f2bu(e*inv);
}

// ---------------- pw scatter + o2 = pw@embv + pf.tabs ----------------
__global__ __launch_bounds__(256) void pw_kernel(
    const unsigned short* __restrict__ P,   // ld 1024 shorts, [h][i] rows
    const float* __restrict__ embv,
    const float* __restrict__ lqc_v, const float* __restrict__ lcq_v,
    const float* __restrict__ lqt_v, const float* __restrict__ ltq_v,
    const float* __restrict__ qcr,  const float* __restrict__ cqr,
    const float* __restrict__ qtr,  const float* __restrict__ tqr,
    const int* __restrict__ ct,    const int* __restrict__ pred,
    float* __restrict__ o2)                 // [8][512][128]
{
  int i = blockIdx.x, t = threadIdx.x;
  __shared__ float pw8[8][56];
  __shared__ float pf1s[24], pf2s[24];
  __shared__ int predrow[512];
  __shared__ int ctrow[256];
  for (int k=t; k<8*56; k+=256) ((float*)pw8)[k] = 0.f;
  if (t < 24) { pf1s[t]=0.f; pf2s[t]=0.f; }
  for (int k=t; k<512; k+=256) predrow[k] = pred[i*LL + k];
  if (i >= QQ) { if (t < 256) ctrow[t] = ct[(i-QQ)*(CCC+TTT) + t]; }
  __syncthreads();

  int h = t >> 5, lane = t & 31;
  float qq = 0.f, l1[3] = {0,0,0}, l2[3] = {0,0,0};
  const unsigned short* Prow = P + ((size_t)h*LL + i)*1024;
  for (int jj = 0; jj < 16; ++jj) {
    int j = lane + jj*32;
    float p = b2f(Prow[j]);
    atomicAdd(&pw8[h][predrow[j]], p);
    if (i < QQ) {
      if (j < QQ) qq += p;
      else if (j < QQ+CCC) { const float* r = qcr + (i*CCC + (j-QQ))*3;
        l1[0]+=p*r[0]; l1[1]+=p*r[1]; l1[2]+=p*r[2]; }
      else { const float* r = qtr + (i*TTT + (j-QQ-CCC))*3;
        l2[0]+=p*r[0]; l2[1]+=p*r[1]; l2[2]+=p*r[2]; }
    } else {
      if (j < QQ) {
        const float* r = (i < QQ+CCC) ? cqr + ((i-QQ)*QQ + j)*3
                                      : tqr + ((i-QQ-CCC)*QQ + j)*3;
        l1[0]+=p*r[0]; l1[1]+=p*r[1]; l1[2]+=p*r[2];
      } else {
        atomicAdd(&pw8[h][ctrow[j-QQ]], p);
      }
    }
  }
  if (i < QQ) atomicAdd(&pw8[h][0], qq);
  atomicAdd(&pf1s[h*3+0], l1[0]); atomicAdd(&pf1s[h*3+1], l1[1]); atomicAdd(&pf1s[h*3+2], l1[2]);
  atomicAdd(&pf2s[h*3+0], l2[0]); atomicAdd(&pf2s[h*3+1], l2[1]); atomicAdd(&pf2s[h*3+2], l2[2]);
  __syncthreads();

  const float* tab1; const float* tab2 = nullptr;
  if (i < QQ)          { tab1 = lqc_v; tab2 = lqt_v; }
  else if (i < QQ+CCC) { tab1 = lcq_v; }
  else                 { tab1 = ltq_v; }

  for (int o = t; o < 1024; o += 256) {
    int h2 = o >> 7, d = o & 127;
    float acc = 0.f;
    #pragma unroll 5
    for (int r = 0; r < RR; ++r) acc += pw8[h2][r]*embv[r*128 + d];
    acc += pf1s[h2*3+0]*tab1[d] + pf1s[h2*3+1]*tab1[128+d] + pf1s[h2*3+2]*tab1[256+d];
    if (tab2) acc += pf2s[h2*3+0]*tab2[d] + pf2s[h2*3+1]*tab2[128+d] + pf2s[h2*3+2]*tab2[256+d];
    o2[((size_t)h2*LL + i)*DKK + d] = acc;
  }
}

// ---------------- launch ----------------
extern "C" void kernel_launch(void* const* d_in, const int* in_sizes, int n_in,
                              void* d_out, int out_size, void* d_ws, size_t ws_size,
                              hipStream_t stream)
{
  const float* x    = (const float*)d_in[0];
  const float* qcr  = (const float*)d_in[1];
  const float* cqr  = (const float*)d_in[2];
  const float* qtr  = (const float*)d_in[3];
  const float* tqr  = (const float*)d_in[4];
  const int*   ct   = (const int*)d_in[5];
  const int*   pred = (const int*)d_in[6];
  const int*   mask = (const int*)d_in[7];
  const float* embk = (const float*)d_in[8];
  const float* embv = (const float*)d_in[9];
  const float* lqc_k = (const float*)d_in[10];
  const float* lqc_v = (const float*)d_in[11];
  const float* lcq_k = (const float*)d_in[12];
  const float* lcq_v = (const float*)d_in[13];
  const float* lqt_k = (const float*)d_in[14];
  const float* lqt_v = (const float*)d_in[15];
  const float* ltq_k = (const float*)d_in[16];
  const float* ltq_v = (const float*)d_in[17];
  const float* Wq = (const float*)d_in[18]; const float* bq = (const float*)d_in[19];
  const float* Wk = (const float*)d_in[20]; const float* bk = (const float*)d_in[21];
  const float* Wv = (const float*)d_in[22]; const float* bv = (const float*)d_in[23];
  const float* Wo = (const float*)d_in[24]; const float* bo = (const float*)d_in[25];
  const float* ln1_g = (const float*)d_in[26]; const float* ln1_b = (const float*)d_in[27];
  const float* ln2_g = (const float*)d_in[28]; const float* ln2_b = (const float*)d_in[29];
  const float* W1 = (const float*)d_in[30]; const float* b1 = (const float*)d_in[31];
  const float* W2 = (const float*)d_in[32]; const float* b2 = (const float*)d_in[33];
  float* out = (float*)d_out;

  float* wsf = (float*)d_ws;
  float* S    = wsf;                       // [8][512][512] fp32; P bf16 in-place; later FFN hidden
  float* o2   = S + (size_t)HH*LL*LL;      // [8][512][128] fp32
  float* qe   = o2 + (size_t)HH*LL*DKK;    // [L,H,R]
  float* ql   = qe + LL*HH*RR;             // [4,L,H,3]
  float* bqkv = ql + 4*LL*HH*3;            // [3072]
  unsigned short* ub = (unsigned short*)(bqkv + 3072);
  unsigned short* ybuf_b = ub;                     // [L,D]
  unsigned short* obuf_b = ybuf_b + LL*DD;         // [L,D]
  unsigned short* Qh     = obuf_b + LL*DD;         // [H][L][DK]
  unsigned short* Kh     = Qh + LL*DD;             // [H][L][DK]
  unsigned short* Vt     = Kh + LL*DD;             // [H][DK][L]
  unsigned short* wqkv_b = Vt + LL*DD;             // [3072,1024]
  unsigned short* wo_b   = wqkv_b + (size_t)3*DD*DD;
  unsigned short* w1_b   = wo_b + (size_t)DD*DD;
  unsigned short* w2_b   = w1_b + (size_t)FFF*DD;
  unsigned short* PS     = (unsigned short*)S;     // P bf16, ld 1024 shorts
  unsigned short* hidden = (unsigned short*)S;     // [L][FFF] bf16 (after P dead)

  // 1. weights -> bf16
  conv_kernel<<<(3145728 + 768 + 255)/256, 256, 0, stream>>>(
      Wq, Wk, Wv, Wo, W1, W2, bq, bk, bv, wqkv_b, wo_b, w1_b, w2_b, bqkv);
  // 2. LN1 -> bf16
  ln_bf16_kernel<<<LL, 256, 0, stream>>>(x, ln1_g, ln1_b, ybuf_b);
  // 3. QKV GEMM (128x64 dbuf) with head scatter
  gemm_qkv_db<<<dim3(48, 4), 256, 0, stream>>>(ybuf_b, wqkv_b, bqkv, Qh, Kh, Vt);
  // 4-5. relation dot tables
  qe_kernel<<<dim3(LL, HH), 64, 0, stream>>>(Qh, embk, qe);
  ql_kernel<<<(4*LL*HH*3 + 255)/256, 256, 0, stream>>>(Qh, lqc_k, lqt_k, lcq_k, ltq_k, ql);
  // 6. scores GEMM: S[h] = Qh[h] @ Kh[h]^T
  gemm_db<64,64,0,0,0,0><<<dim3(8, 8, 8), 256, 0, stream>>>(
      Qh, DKK, (size_t)LL*DKK, Kh, DKK, (size_t)LL*DKK,
      nullptr, nullptr, 0, 0, S, LL, (size_t)LL*LL, DKK);
  // 7. bias+mask+softmax in-place -> P bf16
  softmax_kernel<<<dim3(LL, HH), 512, 0, stream>>>(S, qe, ql, qcr, cqr, qtr, tqr,
                                                   ct, pred, mask);
  // 8. pw scatter -> o2
  pw_kernel<<<LL, 256, 0, stream>>>(PS, embv, lqc_v, lcq_v, lqt_v, ltq_v,
                                    qcr, cqr, qtr, tqr, ct, pred, o2);
  // 9. PV GEMM + o2 add -> obuf bf16
  gemm_db<64,64,1,0,1,0><<<dim3(2, 8, 8), 256, 0, stream>>>(
      PS, 1024, (size_t)LL*1024, Vt, LL, (size_t)DKK*LL,
      nullptr, o2, DKK, (size_t)LL*DKK, obuf_b, DD, (size_t)DKK, LL);
  // 10. out-proj + residual(x) -> out
  gemm_db<64,64,0,0,1,1><<<dim3(16, 8, 1), 256, 0, stream>>>(
      obuf_b, DD, 0, wo_b, DD, 0, bo, x, DD, 0, out, DD, 0, DD);
  // 11. LN2 -> bf16
  ln_bf16_kernel<<<LL, 256, 0, stream>>>(out, ln2_g, ln2_b, ybuf_b);
  // 12. FFN1 relu (128x64 dbuf) -> hidden bf16
  gemm_db<128,64,1,1,0,1><<<dim3(64, 4, 1), 256, 0, stream>>>(
      ybuf_b, DD, 0, w1_b, DD, 0, b1, nullptr, 0, 0, hidden, FFF, 0, DD);
  // 13. FFN2 + residual -> out
  gemm_db<64,64,0,0,1,1><<<dim3(16, 8, 1), 256, 0, stream>>>(
      hidden, FFF, 0, w2_b, FFF, 0, b2, out, DD, 0, out, DD, 0, FFF);
}